// Round 16
// baseline (184.929 us; speedup 1.0000x reference)
//
#include <hip/hip_runtime.h>
#include <math.h>

#define BB 8
#define CC 64
#define LHH 128
#define LWW 128
#define HHH 64
#define HWW 64

typedef __attribute__((ext_vector_type(8))) short short8v;
typedef __attribute__((ext_vector_type(4))) float f32x4;

// unaligned-capable float pair (align 4)
typedef struct __attribute__((packed, aligned(4))) {
  float x, y;
} f2u;

// bt layout: [kchunk:18][oc':256][32 shorts]; kchunk = dydx*2+cc.
#define KCHS 8192  // shorts per kchunk slab (256*32)
// sump layout: [b][row:130][px:130][ch:64] bf16; row = 8320 shorts = 16640 B
#define SROWB 16640          // bytes per global row
#define SIMGB (130 * SROWB)  // bytes per image
#define KROWB 8448           // K4 LDS row stride: 66 px * 128 B

__device__ __forceinline__ unsigned short f2bf(float f) {
  unsigned u = __float_as_uint(f);
  unsigned r = (u + 0x7fffu + ((u >> 16) & 1u)) >> 16;
  return (unsigned short)r;
}

// ---------------------------------------------------------------------------
// K1: depthwise 3x3 on high_feature -> h_small (branchless, pair loads),
//  PLUS (appended blocks) prep of B_t kchunk-major.
// ---------------------------------------------------------------------------
__global__ __launch_bounds__(256) void dw_high_prep_kernel(
    const float* __restrict__ hf, const float* __restrict__ w,
    float* __restrict__ out, const float* __restrict__ wflow,
    unsigned short* __restrict__ bt) {
  if (blockIdx.x >= 8192) {  // prep_bt part: 18*256*32 = 147456 elems
    int t = (blockIdx.x - 8192) * 256 + threadIdx.x;
    if (t >= 18 * KCHS) return;
    int kchunk = t / KCHS;
    int rem = t - kchunk * KCHS;
    int oc2 = rem >> 5;
    int kk = rem & 31;
    int dydx = kchunk >> 1;
    int cc = kchunk & 1;
    int ci = cc * 32 + kk;
    int c = oc2 >> 2;
    int j = oc2 & 3;
    int orig = (j >> 1) * 128 + 2 * c + (j & 1);
    bt[t] = f2bf(wflow[(orig * 64 + ci) * 9 + dydx]);
    return;
  }
  int t = blockIdx.x * 256 + threadIdx.x;
  int x = t & 63;
  int y = (t >> 6) & 63;
  int c = (t >> 12) & 63;  // uniform per block -> scalar weight loads
  int b = t >> 18;
  const float* img = hf + ((size_t)(b * CC + c)) * (HHH * HWW);
  const float* wc = w + c * 9;
  const int xm = max(x - 1, 0), xp = min(x + 1, 63);
  const int ym = max(y - 1, 0), yp = min(y + 1, 63);
  const float mL = x > 0 ? 1.f : 0.f, mR = x < 63 ? 1.f : 0.f;
  const float mT = y > 0 ? 1.f : 0.f, mB = y < 63 ? 1.f : 0.f;
  const bool xz = (x == 0);
  const int dxp = xp - xm;
  f2u p0 = *(const f2u*)(img + ym * 64 + xm);
  f2u p1 = *(const f2u*)(img + y * 64 + xm);
  f2u p2 = *(const f2u*)(img + yp * 64 + xm);
  float r0p = img[ym * 64 + xm + dxp];
  float r1p = img[y * 64 + xm + dxp];
  float r2p = img[yp * 64 + xm + dxp];
  float r0x = xz ? p0.x : p0.y;
  float r1x = xz ? p1.x : p1.y;
  float r2x = xz ? p2.x : p2.y;
  float t0 = (wc[0] * mL) * p0.x + wc[1] * r0x + (wc[2] * mR) * r0p;
  float t1 = (wc[3] * mL) * p1.x + wc[4] * r1x + (wc[5] * mR) * r1p;
  float t2 = (wc[6] * mL) * p2.x + wc[7] * r2x + (wc[8] * mR) * r2p;
  out[t] = mT * t0 + t1 + mB * t2;
}

// ---------------------------------------------------------------------------
// K2: grid flat 1024 (b = bid&7, y = bid>>3), block 512.  (unchanged r13)
// ---------------------------------------------------------------------------
__global__ __launch_bounds__(512, 4) void fuse_sum_stats_kernel(
    const float* __restrict__ low, const float* __restrict__ hsm,
    const float* __restrict__ wl, unsigned short* __restrict__ sump,
    float* __restrict__ gate_in) {
  __shared__ unsigned short sumS[128 * 64];  // 16 KB, XOR-swizzled
  __shared__ float sh[4][4][128];            // 8 KB stats
  __shared__ float wS[576];                  // 2.3 KB weights

  const int bid = blockIdx.x;
  const int b = bid & 7;
  const int y = bid >> 3;
  const int tid = threadIdx.x;
  const int x = tid & 127;
  const int q = tid >> 7;
  char* sbase = (char*)sump + (size_t)b * SIMGB;

  // stage depthwise weights (576 floats)
  wS[tid] = wl[tid];
  if (tid < 64) wS[512 + tid] = wl[512 + tid];

  // border zeroing
  {
    const short8v z = {0, 0, 0, 0, 0, 0, 0, 0};
    if (y == 0) {
      for (int i = tid; i < 2080; i += 512) {
        int row = (i < 1040) ? 0 : 129;
        int o = (i % 1040) * 16;
        *(short8v*)(sbase + (size_t)row * SROWB + o) = z;
      }
    }
    if (tid < 16) {
      int side = tid >> 3;
      int o = (tid & 7) * 16;
      *(short8v*)(sbase + (size_t)(y + 1) * SROWB + side * (129 * 128) + o) = z;
    }
  }
  __syncthreads();

  // bilinear-up coords (64 -> 128, half-pixel)
  float sy = 0.5f * y - 0.25f;
  float sx = 0.5f * x - 0.25f;
  float y0f = floorf(sy), x0f = floorf(sx);
  float wy = sy - y0f, wx = sx - x0f;
  int iy0 = (int)y0f, ix0 = (int)x0f;
  int iy0c = max(0, min(HHH - 1, iy0));
  int iy1c = max(0, min(HHH - 1, iy0 + 1));
  float w00 = (1.f - wy) * (1.f - wx), w01 = (1.f - wy) * wx;
  float w10 = wy * (1.f - wx), w11 = wy * wx;
  const int hxb = min(max(ix0, 0), HWW - 2);
  const bool hs0 = (ix0 <= hxb);
  const bool hs1 = (ix0 + 1 <= hxb);

  const int xm = max(x - 1, 0), xp = min(x + 1, 127);
  const int ym = max(y - 1, 0), yp = min(y + 1, 127);
  const float mL = x > 0 ? 1.f : 0.f, mR = x < 127 ? 1.f : 0.f;
  const float mT = y > 0 ? 1.f : 0.f, mB = y < 127 ? 1.f : 0.f;
  const bool xz = (x == 0);

  const unsigned lco = (unsigned)((b * CC + q * 16) * 16384);
  const unsigned hco = (unsigned)((b * CC + q * 16) * 4096);
  const unsigned ro0 = (unsigned)(ym * 128 + xm);
  const unsigned ro1 = (unsigned)(y * 128 + xm);
  const unsigned ro2 = (unsigned)(yp * 128 + xm);
  const unsigned dxp = (unsigned)(xp - xm);
  const unsigned ho0 = (unsigned)(iy0c * 64 + hxb);
  const unsigned ho1 = (unsigned)(iy1c * 64 + hxb);

  float hmean = 0.f, lmean = 0.f;
  float hmax = -3.402823466e+38f, lmax = -3.402823466e+38f;

  unsigned short sv[16];
#pragma unroll 8
  for (int j = 0; j < 16; ++j) {
    const unsigned lo_ = lco + (unsigned)(j * 16384);
    const float* wc = &wS[(q * 16 + j) * 9];
    f2u p0 = *(const f2u*)(low + (lo_ + ro0));
    f2u p1 = *(const f2u*)(low + (lo_ + ro1));
    f2u p2 = *(const f2u*)(low + (lo_ + ro2));
    float r0p = low[lo_ + ro0 + dxp];
    float r1p = low[lo_ + ro1 + dxp];
    float r2p = low[lo_ + ro2 + dxp];
    const unsigned ho_ = hco + (unsigned)(j * 4096);
    f2u q0 = *(const f2u*)(hsm + (ho_ + ho0));
    f2u q1 = *(const f2u*)(hsm + (ho_ + ho1));

    float r0x = xz ? p0.x : p0.y;
    float r1x = xz ? p1.x : p1.y;
    float r2x = xz ? p2.x : p2.y;
    float t0 = (wc[0] * mL) * p0.x + wc[1] * r0x + (wc[2] * mR) * r0p;
    float t1 = (wc[3] * mL) * p1.x + wc[4] * r1x + (wc[5] * mR) * r1p;
    float t2 = (wc[6] * mL) * p2.x + wc[7] * r2x + (wc[8] * mR) * r2p;
    float l = mT * t0 + t1 + mB * t2;

    float h00 = hs0 ? q0.x : q0.y;
    float h01 = hs1 ? q0.x : q0.y;
    float h10 = hs0 ? q1.x : q1.y;
    float h11 = hs1 ? q1.x : q1.y;
    float h = w00 * h00 + w01 * h01 + w10 * h10 + w11 * h11;

    sv[j] = f2bf(l + h);
    hmean += h;
    lmean += l;
    hmax = fmaxf(hmax, h);
    lmax = fmaxf(lmax, l);
  }

  // pack 16 shorts -> two b128 LDS writes at swizzled addr
  {
    unsigned int pk[8];
#pragma unroll
    for (int j = 0; j < 8; ++j)
      pk[j] = (unsigned)sv[2 * j] | ((unsigned)sv[2 * j + 1] << 16);
    const int u0 = (x * 128 + q * 32) ^ ((x & 7) << 4);
    const int u1 = (x * 128 + q * 32 + 16) ^ ((x & 7) << 4);
    *(short8v*)((char*)sumS + u0) = *(short8v*)&pk[0];
    *(short8v*)((char*)sumS + u1) = *(short8v*)&pk[4];
  }
  sh[0][q][x] = hmean;
  sh[1][q][x] = lmean;
  sh[2][q][x] = hmax;
  sh[3][q][x] = lmax;
  __syncthreads();

  // coalesced write-out: 16 KB -> global row (y+1), px 1..128
  {
    char* dst = sbase + (size_t)(y + 1) * SROWB + 128;
#pragma unroll
    for (int pass = 0; pass < 2; ++pass) {
      int o = (tid + pass * 512) * 16;
      int L = o ^ (((o >> 7) & 7) << 4);
      *(short8v*)(dst + o) = *(const short8v*)((const char*)sumS + L);
    }
  }
  // stats reduce
  {
    const int s = q;
    float v0 = sh[s][0][x], v1 = sh[s][1][x], v2 = sh[s][2][x],
          v3 = sh[s][3][x];
    float r;
    if (s < 2)
      r = (v0 + v1 + v2 + v3) * (1.0f / CC);
    else
      r = fmaxf(fmaxf(v0, v1), fmaxf(v2, v3));
    gate_in[((size_t)(b * 4 + s)) * 16384 + y * 128 + x] = r;
  }
}

// ---------------------------------------------------------------------------
// batched branchless bilinear: prep / fin split.
// ---------------------------------------------------------------------------
struct BSamp {
  f2u p0, p1;
  float mx0, mx1, my0, my1;
  bool s0, s1;
};

__device__ __forceinline__ BSamp bprep(const float* __restrict__ base,
                                       unsigned coff, int H, int W, float gx,
                                       float gy) {
  BSamp s;
  float x0f = floorf(gx), y0f = floorf(gy);
  float wx1 = gx - x0f, wy1 = gy - y0f;
  int x0 = (int)x0f, y0 = (int)y0f;
  int y1 = y0 + 1;
  s.mx0 = ((unsigned)x0 < (unsigned)W) ? 1.f - wx1 : 0.f;
  s.mx1 = ((unsigned)(x0 + 1) < (unsigned)W) ? wx1 : 0.f;
  s.my0 = ((unsigned)y0 < (unsigned)H) ? 1.f - wy1 : 0.f;
  s.my1 = ((unsigned)y1 < (unsigned)H) ? wy1 : 0.f;
  int xb = min(max(x0, 0), W - 2);
  int y0c = min(max(y0, 0), H - 1);
  int y1c = min(max(y1, 0), H - 1);
  s.p0 = *(const f2u*)(base + (coff + (unsigned)(y0c * W + xb)));
  s.p1 = *(const f2u*)(base + (coff + (unsigned)(y1c * W + xb)));
  s.s0 = (x0 <= xb);
  s.s1 = (x0 + 1 <= xb);
  return s;
}

__device__ __forceinline__ float bfin(const BSamp& s) {
  float v00 = s.s0 ? s.p0.x : s.p0.y;
  float v01 = s.s1 ? s.p0.x : s.p0.y;
  float v10 = s.s0 ? s.p1.x : s.p1.y;
  float v11 = s.s1 ? s.p1.x : s.p1.y;
  return s.my0 * (s.mx0 * v00 + s.mx1 * v01) +
         s.my1 * (s.mx0 * v10 + s.mx1 * v11);
}

// ---------------------------------------------------------------------------
// K4: fused gate-conv + flow-GEMM + warp + blend; TWO output rows per block.
//  grid flat 1024: b = bid&7 (XCD), ypair = (bid>>3)&63, xh = bid>>9.
//  r14 layout (XOR swizzle, 0 conflicts) with HOISTED swizzled bases:
//  fa(mf) = fa(0) + mf*2048 exactly (XOR bits 4-6 disjoint from mf*2048,
//  p&7 invariant under mf*16) -> ds_read immediates, ~3x less addr VALU.
// ---------------------------------------------------------------------------
__global__ __launch_bounds__(512, 4) void flow_gemm_combine_kernel(
    const unsigned short* __restrict__ sump,
    const unsigned short* __restrict__ bt, const float* __restrict__ low,
    const float* __restrict__ high, const float* __restrict__ gate_in,
    const float* __restrict__ wg, float* __restrict__ out) {
  __shared__ unsigned short ldsU[4 * 4224];  // 33792 B (4 rows x 66 px)
  __shared__ float gateS[128];

  const int bid = blockIdx.x;
  const int b = bid & 7;
  const int ypair = (bid >> 3) & 63;
  const int xh = bid >> 9;
  const int y0 = ypair * 2;
  const int tid = threadIdx.x;
  const int lane = tid & 63;
  const int wid = tid >> 6;  // oc' block = wid*32
  const int lr = lane & 15;
  const int lg = lane >> 4;

  // ---- stage padded rows y0..y0+3, px window xh*64 .. xh*64+65
  {
    const char* src =
        (const char*)sump + (size_t)b * SIMGB + (size_t)y0 * SROWB + xh * 8192;
    char* dstb = (char*)ldsU;
#pragma unroll
    for (int pass = 0; pass < 4; ++pass) {
      int i = tid + pass * 512;
      int seg = i / 528;
      int wo = (i - seg * 528) * 16;
      int o = seg * KROWB + wo;
      int L = o ^ (((o >> 7) & 7) << 4);
      *(short8v*)(dstb + L) = *(const short8v*)(src + seg * SROWB + wo);
    }
    if (tid < 64) {
      int i = tid + 2048;
      int seg = i / 528;
      int wo = (i - seg * 528) * 16;
      int o = seg * KROWB + wo;
      int L = o ^ (((o >> 7) & 7) << 4);
      *(short8v*)(dstb + L) = *(const short8v*)(src + seg * SROWB + wo);
    }
  }

  // ---- gate conv for 128 px (2 rows x 64 px), waves 0-1, branchless
  if (tid < 128) {
    const int r = tid >> 6;
    const int x = xh * 64 + (tid & 63);
    const int y = y0 + r;
    const int xm = max(x - 1, 0), xp = min(x + 1, 127);
    const int ym = max(y - 1, 0), yp = min(y + 1, 127);
    const float mL = x > 0 ? 1.f : 0.f, mR = x < 127 ? 1.f : 0.f;
    const float mT = y > 0 ? 1.f : 0.f, mB = y < 127 ? 1.f : 0.f;
    const float* gi = gate_in + (size_t)b * 4 * 16384;
    float acc0 = 0.f;
#pragma unroll
    for (int ic = 0; ic < 4; ++ic) {
      const float* img = gi + ic * 16384;
      const float* wc = wg + ic * 9;
      const float* r0 = img + ym * 128;
      const float* r1 = img + y * 128;
      const float* r2 = img + yp * 128;
      float t0 = (wc[0] * mL) * r0[xm] + wc[1] * r0[x] + (wc[2] * mR) * r0[xp];
      float t1 = (wc[3] * mL) * r1[xm] + wc[4] * r1[x] + (wc[5] * mR) * r1[xp];
      float t2 = (wc[6] * mL) * r2[xm] + wc[7] * r2[x] + (wc[8] * mR) * r2[xp];
      acc0 += mT * t0 + t1 + mB * t2;
    }
    gateS[tid] = 1.0f / (1.0f + expf(-acc0));
  }
  __syncthreads();

  f32x4 acc0[4][2], acc1[4][2];
#pragma unroll
  for (int i = 0; i < 4; ++i)
#pragma unroll
    for (int j = 0; j < 2; ++j) {
      acc0[i][j] = (f32x4){0.f, 0.f, 0.f, 0.f};
      acc1[i][j] = (f32x4){0.f, 0.f, 0.f, 0.f};
    }

  const char* rc = (const char*)ldsU;
  // kchunk-major bt: coalesced 1024B wave accesses
  const unsigned short* btw = bt + (wid * 32 + lr) * 32 + lg * 8;
  const int lgo = lg * 16;
  for (int dydx = 0; dydx < 9; ++dydx) {
    const int dy = dydx / 3;
    const int dxl = dydx - dy * 3;
    const int p0r0 = dy * 66 + dxl + lr;  // row0 base pixel (mf=0)
    const int p0r1 = p0r0 + 66;           // row1 base pixel
#pragma unroll
    for (int cc = 0; cc < 2; ++cc) {
      const int kchunk = dydx * 2 + cc;
      // hoisted swizzled bases; mf adds +2048 (immediate offsets)
      const unsigned ba0 =
          (unsigned)((p0r0 * 128 + cc * 64 + lgo) ^ ((p0r0 & 7) << 4));
      const unsigned ba1 =
          (unsigned)((p0r1 * 128 + cc * 64 + lgo) ^ ((p0r1 & 7) << 4));
      short8v af0[4], af1[4], bfr[2];
#pragma unroll
      for (int nf = 0; nf < 2; ++nf)
        bfr[nf] = *(const short8v*)&btw[kchunk * KCHS + nf * 16 * 32];
#pragma unroll
      for (int mf = 0; mf < 4; ++mf) {
        af0[mf] = *(const short8v*)(rc + ba0 + mf * 2048);
        af1[mf] = *(const short8v*)(rc + ba1 + mf * 2048);
      }
      // swapped operands: D = [oc' x px]
#pragma unroll
      for (int mf = 0; mf < 4; ++mf)
#pragma unroll
        for (int nf = 0; nf < 2; ++nf) {
          acc0[mf][nf] = __builtin_amdgcn_mfma_f32_16x16x32_bf16(
              bfr[nf], af0[mf], acc0[mf][nf], 0, 0, 0);
          acc1[mf][nf] = __builtin_amdgcn_mfma_f32_16x16x32_bf16(
              bfr[nf], af1[mf], acc1[mf][nf], 0, 0, 0);
        }
    }
  }

  // ---- combine, per row, from registers (compile-time acc binding)
  const float* lowb = low + (size_t)b * CC * 16384;
  const float* highb = high + (size_t)b * CC * 4096;
  float* outb = out + (size_t)b * CC * 16384;
  const int xg0 = xh * 64;
  const int c0 = wid * 8 + lg;
  const int c1 = c0 + 4;

  auto combine_row = [&](const f32x4(&ac)[4][2], int y, int gbase) {
    const float by = -1.0f + y * (2.0f / 127.0f);
    const float gyh_b = (by + 1.0f) * 31.5f;
    const float gyl_b = (by + 1.0f) * 63.5f;
#pragma unroll
    for (int mf = 0; mf < 4; ++mf) {
      const int x = xg0 + mf * 16 + lr;
      const float g = gateS[gbase + mf * 16 + lr];
      const float bx = -1.0f + x * (2.0f / 127.0f);
      const float gxh_b = (bx + 1.0f) * 31.5f;
      const float gxl_b = (bx + 1.0f) * 63.5f;

      BSamp sh0 = bprep(highb, (unsigned)(c0 * 4096), HHH, HWW,
                        fmaf(ac[mf][0][0], 63.0f / 256.0f, gxh_b),
                        fmaf(ac[mf][0][1], 63.0f / 256.0f, gyh_b));
      BSamp sl0 = bprep(lowb, (unsigned)(c0 * 16384), LHH, LWW,
                        fmaf(ac[mf][0][2], 127.0f / 256.0f, gxl_b),
                        fmaf(ac[mf][0][3], 127.0f / 256.0f, gyl_b));
      BSamp sh1 = bprep(highb, (unsigned)(c1 * 4096), HHH, HWW,
                        fmaf(ac[mf][1][0], 63.0f / 256.0f, gxh_b),
                        fmaf(ac[mf][1][1], 63.0f / 256.0f, gyh_b));
      BSamp sl1 = bprep(lowb, (unsigned)(c1 * 16384), LHH, LWW,
                        fmaf(ac[mf][1][2], 127.0f / 256.0f, gxl_b),
                        fmaf(ac[mf][1][3], 127.0f / 256.0f, gyl_b));

      float h0 = bfin(sh0), l0 = bfin(sl0);
      outb[(unsigned)(c0 * 16384 + y * 128 + x)] = fmaf(g, h0 - l0, l0);
      float h1 = bfin(sh1), l1 = bfin(sl1);
      outb[(unsigned)(c1 * 16384 + y * 128 + x)] = fmaf(g, h1 - l1, l1);
    }
  };

  combine_row(acc0, y0, 0);
  combine_row(acc1, y0 + 1, 64);
}

// ---------------------------------------------------------------------------
extern "C" void kernel_launch(void* const* d_in, const int* in_sizes, int n_in,
                              void* d_out, int out_size, void* d_ws,
                              size_t ws_size, hipStream_t stream) {
  const float* low = (const float*)d_in[0];
  const float* high = (const float*)d_in[1];
  const float* w_conv_l = (const float*)d_in[2];
  const float* w_conv_h = (const float*)d_in[3];
  const float* w_flow = (const float*)d_in[4];
  const float* w_gate = (const float*)d_in[5];
  float* out = (float*)d_out;
  char* ws = (char*)d_ws;

  const size_t OFF_HSMALL = 0;         //  8,388,608
  const size_t OFF_SUMP = 8388608;     // 17,305,600 (bf16 [b][row][px][ch])
  const size_t OFF_GATEIN = 25694208;  //  2,097,152
  const size_t OFF_BT = 28315648;      //    294,912 (18*256*32 shorts)

  float* h_small = (float*)(ws + OFF_HSMALL);
  unsigned short* sump = (unsigned short*)(ws + OFF_SUMP);
  float* gate_in = (float*)(ws + OFF_GATEIN);
  unsigned short* bt = (unsigned short*)(ws + OFF_BT);

  // K1: dw-high (8192 blocks) + prep_bt (576 blocks appended)
  dw_high_prep_kernel<<<8192 + 576, 256, 0, stream>>>(high, w_conv_h, h_small,
                                                      w_flow, bt);
  // K2: sum + stats + sump borders
  fuse_sum_stats_kernel<<<1024, 512, 0, stream>>>(low, h_small, w_conv_l, sump,
                                                  gate_in);
  // K4: gate conv + flow GEMM + warp + blend (2 rows/block, hoisted bases)
  flow_gemm_combine_kernel<<<1024, 512, 0, stream>>>(sump, bt, low, high,
                                                     gate_in, w_gate, out);
}

// Round 17
// 94.565 us; speedup vs baseline: 1.9556x; 1.9556x over previous
//
#include <hip/hip_runtime.h>
#include <math.h>

#define BB 8
#define CC 64
#define LHH 128
#define LWW 128
#define HHH 64
#define HWW 64

typedef __attribute__((ext_vector_type(8))) short short8v;
typedef __attribute__((ext_vector_type(4))) float f32x4;

// unaligned-capable float pair (align 4)
typedef struct __attribute__((packed, aligned(4))) {
  float x, y;
} f2u;

// bt layout: [kchunk:18][oc':256][32 shorts]; kchunk = dydx*2+cc.
#define KCHS 8192  // shorts per kchunk slab (256*32)
// sump layout: [b][row:130][px:130][ch:64] bf16; row = 8320 shorts = 16640 B
#define SROWB 16640          // bytes per global row
#define SIMGB (130 * SROWB)  // bytes per image
#define KROWB 8448           // K4 LDS row stride: 66 px * 128 B

__device__ __forceinline__ unsigned short f2bf(float f) {
  unsigned u = __float_as_uint(f);
  unsigned r = (u + 0x7fffu + ((u >> 16) & 1u)) >> 16;
  return (unsigned short)r;
}

// ---------------------------------------------------------------------------
// K1: depthwise 3x3 on high_feature -> h_small (branchless, pair loads),
//  PLUS (appended blocks) prep of B_t kchunk-major.
// ---------------------------------------------------------------------------
__global__ __launch_bounds__(256) void dw_high_prep_kernel(
    const float* __restrict__ hf, const float* __restrict__ w,
    float* __restrict__ out, const float* __restrict__ wflow,
    unsigned short* __restrict__ bt) {
  if (blockIdx.x >= 8192) {  // prep_bt part: 18*256*32 = 147456 elems
    int t = (blockIdx.x - 8192) * 256 + threadIdx.x;
    if (t >= 18 * KCHS) return;
    int kchunk = t / KCHS;
    int rem = t - kchunk * KCHS;
    int oc2 = rem >> 5;
    int kk = rem & 31;
    int dydx = kchunk >> 1;
    int cc = kchunk & 1;
    int ci = cc * 32 + kk;
    int c = oc2 >> 2;
    int j = oc2 & 3;
    int orig = (j >> 1) * 128 + 2 * c + (j & 1);
    bt[t] = f2bf(wflow[(orig * 64 + ci) * 9 + dydx]);
    return;
  }
  int t = blockIdx.x * 256 + threadIdx.x;
  int x = t & 63;
  int y = (t >> 6) & 63;
  int c = (t >> 12) & 63;  // uniform per block -> scalar weight loads
  int b = t >> 18;
  const float* img = hf + ((size_t)(b * CC + c)) * (HHH * HWW);
  const float* wc = w + c * 9;
  const int xm = max(x - 1, 0), xp = min(x + 1, 63);
  const int ym = max(y - 1, 0), yp = min(y + 1, 63);
  const float mL = x > 0 ? 1.f : 0.f, mR = x < 63 ? 1.f : 0.f;
  const float mT = y > 0 ? 1.f : 0.f, mB = y < 63 ? 1.f : 0.f;
  const bool xz = (x == 0);
  const int dxp = xp - xm;
  f2u p0 = *(const f2u*)(img + ym * 64 + xm);
  f2u p1 = *(const f2u*)(img + y * 64 + xm);
  f2u p2 = *(const f2u*)(img + yp * 64 + xm);
  float r0p = img[ym * 64 + xm + dxp];
  float r1p = img[y * 64 + xm + dxp];
  float r2p = img[yp * 64 + xm + dxp];
  float r0x = xz ? p0.x : p0.y;
  float r1x = xz ? p1.x : p1.y;
  float r2x = xz ? p2.x : p2.y;
  float t0 = (wc[0] * mL) * p0.x + wc[1] * r0x + (wc[2] * mR) * r0p;
  float t1 = (wc[3] * mL) * p1.x + wc[4] * r1x + (wc[5] * mR) * r1p;
  float t2 = (wc[6] * mL) * p2.x + wc[7] * r2x + (wc[8] * mR) * r2p;
  out[t] = mT * t0 + t1 + mB * t2;
}

// ---------------------------------------------------------------------------
// K2: grid flat 1024 (b = bid&7, y = bid>>3), block 512.  (unchanged r13)
// ---------------------------------------------------------------------------
__global__ __launch_bounds__(512, 4) void fuse_sum_stats_kernel(
    const float* __restrict__ low, const float* __restrict__ hsm,
    const float* __restrict__ wl, unsigned short* __restrict__ sump,
    float* __restrict__ gate_in) {
  __shared__ unsigned short sumS[128 * 64];  // 16 KB, XOR-swizzled
  __shared__ float sh[4][4][128];            // 8 KB stats
  __shared__ float wS[576];                  // 2.3 KB weights

  const int bid = blockIdx.x;
  const int b = bid & 7;
  const int y = bid >> 3;
  const int tid = threadIdx.x;
  const int x = tid & 127;
  const int q = tid >> 7;
  char* sbase = (char*)sump + (size_t)b * SIMGB;

  // stage depthwise weights (576 floats)
  wS[tid] = wl[tid];
  if (tid < 64) wS[512 + tid] = wl[512 + tid];

  // border zeroing
  {
    const short8v z = {0, 0, 0, 0, 0, 0, 0, 0};
    if (y == 0) {
      for (int i = tid; i < 2080; i += 512) {
        int row = (i < 1040) ? 0 : 129;
        int o = (i % 1040) * 16;
        *(short8v*)(sbase + (size_t)row * SROWB + o) = z;
      }
    }
    if (tid < 16) {
      int side = tid >> 3;
      int o = (tid & 7) * 16;
      *(short8v*)(sbase + (size_t)(y + 1) * SROWB + side * (129 * 128) + o) = z;
    }
  }
  __syncthreads();

  // bilinear-up coords (64 -> 128, half-pixel)
  float sy = 0.5f * y - 0.25f;
  float sx = 0.5f * x - 0.25f;
  float y0f = floorf(sy), x0f = floorf(sx);
  float wy = sy - y0f, wx = sx - x0f;
  int iy0 = (int)y0f, ix0 = (int)x0f;
  int iy0c = max(0, min(HHH - 1, iy0));
  int iy1c = max(0, min(HHH - 1, iy0 + 1));
  float w00 = (1.f - wy) * (1.f - wx), w01 = (1.f - wy) * wx;
  float w10 = wy * (1.f - wx), w11 = wy * wx;
  const int hxb = min(max(ix0, 0), HWW - 2);
  const bool hs0 = (ix0 <= hxb);
  const bool hs1 = (ix0 + 1 <= hxb);

  const int xm = max(x - 1, 0), xp = min(x + 1, 127);
  const int ym = max(y - 1, 0), yp = min(y + 1, 127);
  const float mL = x > 0 ? 1.f : 0.f, mR = x < 127 ? 1.f : 0.f;
  const float mT = y > 0 ? 1.f : 0.f, mB = y < 127 ? 1.f : 0.f;
  const bool xz = (x == 0);

  const unsigned lco = (unsigned)((b * CC + q * 16) * 16384);
  const unsigned hco = (unsigned)((b * CC + q * 16) * 4096);
  const unsigned ro0 = (unsigned)(ym * 128 + xm);
  const unsigned ro1 = (unsigned)(y * 128 + xm);
  const unsigned ro2 = (unsigned)(yp * 128 + xm);
  const unsigned dxp = (unsigned)(xp - xm);
  const unsigned ho0 = (unsigned)(iy0c * 64 + hxb);
  const unsigned ho1 = (unsigned)(iy1c * 64 + hxb);

  float hmean = 0.f, lmean = 0.f;
  float hmax = -3.402823466e+38f, lmax = -3.402823466e+38f;

  unsigned short sv[16];
#pragma unroll 8
  for (int j = 0; j < 16; ++j) {
    const unsigned lo_ = lco + (unsigned)(j * 16384);
    const float* wc = &wS[(q * 16 + j) * 9];
    f2u p0 = *(const f2u*)(low + (lo_ + ro0));
    f2u p1 = *(const f2u*)(low + (lo_ + ro1));
    f2u p2 = *(const f2u*)(low + (lo_ + ro2));
    float r0p = low[lo_ + ro0 + dxp];
    float r1p = low[lo_ + ro1 + dxp];
    float r2p = low[lo_ + ro2 + dxp];
    const unsigned ho_ = hco + (unsigned)(j * 4096);
    f2u q0 = *(const f2u*)(hsm + (ho_ + ho0));
    f2u q1 = *(const f2u*)(hsm + (ho_ + ho1));

    float r0x = xz ? p0.x : p0.y;
    float r1x = xz ? p1.x : p1.y;
    float r2x = xz ? p2.x : p2.y;
    float t0 = (wc[0] * mL) * p0.x + wc[1] * r0x + (wc[2] * mR) * r0p;
    float t1 = (wc[3] * mL) * p1.x + wc[4] * r1x + (wc[5] * mR) * r1p;
    float t2 = (wc[6] * mL) * p2.x + wc[7] * r2x + (wc[8] * mR) * r2p;
    float l = mT * t0 + t1 + mB * t2;

    float h00 = hs0 ? q0.x : q0.y;
    float h01 = hs1 ? q0.x : q0.y;
    float h10 = hs0 ? q1.x : q1.y;
    float h11 = hs1 ? q1.x : q1.y;
    float h = w00 * h00 + w01 * h01 + w10 * h10 + w11 * h11;

    sv[j] = f2bf(l + h);
    hmean += h;
    lmean += l;
    hmax = fmaxf(hmax, h);
    lmax = fmaxf(lmax, l);
  }

  // pack 16 shorts -> two b128 LDS writes at swizzled addr
  {
    unsigned int pk[8];
#pragma unroll
    for (int j = 0; j < 8; ++j)
      pk[j] = (unsigned)sv[2 * j] | ((unsigned)sv[2 * j + 1] << 16);
    const int u0 = (x * 128 + q * 32) ^ ((x & 7) << 4);
    const int u1 = (x * 128 + q * 32 + 16) ^ ((x & 7) << 4);
    *(short8v*)((char*)sumS + u0) = *(short8v*)&pk[0];
    *(short8v*)((char*)sumS + u1) = *(short8v*)&pk[4];
  }
  sh[0][q][x] = hmean;
  sh[1][q][x] = lmean;
  sh[2][q][x] = hmax;
  sh[3][q][x] = lmax;
  __syncthreads();

  // coalesced write-out: 16 KB -> global row (y+1), px 1..128
  {
    char* dst = sbase + (size_t)(y + 1) * SROWB + 128;
#pragma unroll
    for (int pass = 0; pass < 2; ++pass) {
      int o = (tid + pass * 512) * 16;
      int L = o ^ (((o >> 7) & 7) << 4);
      *(short8v*)(dst + o) = *(const short8v*)((const char*)sumS + L);
    }
  }
  // stats reduce
  {
    const int s = q;
    float v0 = sh[s][0][x], v1 = sh[s][1][x], v2 = sh[s][2][x],
          v3 = sh[s][3][x];
    float r;
    if (s < 2)
      r = (v0 + v1 + v2 + v3) * (1.0f / CC);
    else
      r = fmaxf(fmaxf(v0, v1), fmaxf(v2, v3));
    gate_in[((size_t)(b * 4 + s)) * 16384 + y * 128 + x] = r;
  }
}

// ---------------------------------------------------------------------------
// batched branchless bilinear: prep / fin split.
// ---------------------------------------------------------------------------
struct BSamp {
  f2u p0, p1;
  float mx0, mx1, my0, my1;
  bool s0, s1;
};

__device__ __forceinline__ BSamp bprep(const float* __restrict__ base,
                                       unsigned coff, int H, int W, float gx,
                                       float gy) {
  BSamp s;
  float x0f = floorf(gx), y0f = floorf(gy);
  float wx1 = gx - x0f, wy1 = gy - y0f;
  int x0 = (int)x0f, y0 = (int)y0f;
  int y1 = y0 + 1;
  s.mx0 = ((unsigned)x0 < (unsigned)W) ? 1.f - wx1 : 0.f;
  s.mx1 = ((unsigned)(x0 + 1) < (unsigned)W) ? wx1 : 0.f;
  s.my0 = ((unsigned)y0 < (unsigned)H) ? 1.f - wy1 : 0.f;
  s.my1 = ((unsigned)y1 < (unsigned)H) ? wy1 : 0.f;
  int xb = min(max(x0, 0), W - 2);
  int y0c = min(max(y0, 0), H - 1);
  int y1c = min(max(y1, 0), H - 1);
  s.p0 = *(const f2u*)(base + (coff + (unsigned)(y0c * W + xb)));
  s.p1 = *(const f2u*)(base + (coff + (unsigned)(y1c * W + xb)));
  s.s0 = (x0 <= xb);
  s.s1 = (x0 + 1 <= xb);
  return s;
}

__device__ __forceinline__ float bfin(const BSamp& s) {
  float v00 = s.s0 ? s.p0.x : s.p0.y;
  float v01 = s.s1 ? s.p0.x : s.p0.y;
  float v10 = s.s0 ? s.p1.x : s.p1.y;
  float v11 = s.s1 ? s.p1.x : s.p1.y;
  return s.my0 * (s.mx0 * v00 + s.mx1 * v01) +
         s.my1 * (s.mx0 * v10 + s.mx1 * v11);
}

// ---------------------------------------------------------------------------
// K4: fused gate-conv + flow-GEMM + warp + blend; TWO output rows per block.
//  grid flat 1024: b = bid&7 (XCD), ypair = (bid>>3)&63, xh = bid>>9.
//  r14 layout (XOR swizzle, 0 conflicts) + hoisted swizzled bases
//  (fa(mf) = fa(0) + mf*2048 exactly) + #pragma unroll 1 on the dydx loop
//  to PREVENT full unroll -> bounded live ranges, no acc spill (r15/r16
//  lesson: simple addresses + full unroll = load hoisting = scratch spill).
// ---------------------------------------------------------------------------
__global__ __launch_bounds__(512, 4) void flow_gemm_combine_kernel(
    const unsigned short* __restrict__ sump,
    const unsigned short* __restrict__ bt, const float* __restrict__ low,
    const float* __restrict__ high, const float* __restrict__ gate_in,
    const float* __restrict__ wg, float* __restrict__ out) {
  __shared__ unsigned short ldsU[4 * 4224];  // 33792 B (4 rows x 66 px)
  __shared__ float gateS[128];

  const int bid = blockIdx.x;
  const int b = bid & 7;
  const int ypair = (bid >> 3) & 63;
  const int xh = bid >> 9;
  const int y0 = ypair * 2;
  const int tid = threadIdx.x;
  const int lane = tid & 63;
  const int wid = tid >> 6;  // oc' block = wid*32
  const int lr = lane & 15;
  const int lg = lane >> 4;

  // ---- stage padded rows y0..y0+3, px window xh*64 .. xh*64+65
  {
    const char* src =
        (const char*)sump + (size_t)b * SIMGB + (size_t)y0 * SROWB + xh * 8192;
    char* dstb = (char*)ldsU;
#pragma unroll
    for (int pass = 0; pass < 4; ++pass) {
      int i = tid + pass * 512;
      int seg = i / 528;
      int wo = (i - seg * 528) * 16;
      int o = seg * KROWB + wo;
      int L = o ^ (((o >> 7) & 7) << 4);
      *(short8v*)(dstb + L) = *(const short8v*)(src + seg * SROWB + wo);
    }
    if (tid < 64) {
      int i = tid + 2048;
      int seg = i / 528;
      int wo = (i - seg * 528) * 16;
      int o = seg * KROWB + wo;
      int L = o ^ (((o >> 7) & 7) << 4);
      *(short8v*)(dstb + L) = *(const short8v*)(src + seg * SROWB + wo);
    }
  }

  // ---- gate conv for 128 px (2 rows x 64 px), waves 0-1, branchless
  if (tid < 128) {
    const int r = tid >> 6;
    const int x = xh * 64 + (tid & 63);
    const int y = y0 + r;
    const int xm = max(x - 1, 0), xp = min(x + 1, 127);
    const int ym = max(y - 1, 0), yp = min(y + 1, 127);
    const float mL = x > 0 ? 1.f : 0.f, mR = x < 127 ? 1.f : 0.f;
    const float mT = y > 0 ? 1.f : 0.f, mB = y < 127 ? 1.f : 0.f;
    const float* gi = gate_in + (size_t)b * 4 * 16384;
    float acc0 = 0.f;
#pragma unroll
    for (int ic = 0; ic < 4; ++ic) {
      const float* img = gi + ic * 16384;
      const float* wc = wg + ic * 9;
      const float* r0 = img + ym * 128;
      const float* r1 = img + y * 128;
      const float* r2 = img + yp * 128;
      float t0 = (wc[0] * mL) * r0[xm] + wc[1] * r0[x] + (wc[2] * mR) * r0[xp];
      float t1 = (wc[3] * mL) * r1[xm] + wc[4] * r1[x] + (wc[5] * mR) * r1[xp];
      float t2 = (wc[6] * mL) * r2[xm] + wc[7] * r2[x] + (wc[8] * mR) * r2[xp];
      acc0 += mT * t0 + t1 + mB * t2;
    }
    gateS[tid] = 1.0f / (1.0f + expf(-acc0));
  }
  __syncthreads();

  f32x4 acc0[4][2], acc1[4][2];
#pragma unroll
  for (int i = 0; i < 4; ++i)
#pragma unroll
    for (int j = 0; j < 2; ++j) {
      acc0[i][j] = (f32x4){0.f, 0.f, 0.f, 0.f};
      acc1[i][j] = (f32x4){0.f, 0.f, 0.f, 0.f};
    }

  const char* rc = (const char*)ldsU;
  // kchunk-major bt: coalesced 1024B wave accesses
  const unsigned short* btw = bt + (wid * 32 + lr) * 32 + lg * 8;
  const int lgo = lg * 16;
#pragma unroll 1
  for (int dydx = 0; dydx < 9; ++dydx) {
    const int dy = dydx / 3;
    const int dxl = dydx - dy * 3;
    const int p0r0 = dy * 66 + dxl + lr;  // row0 base pixel (mf=0)
    const int p0r1 = p0r0 + 66;           // row1 base pixel
#pragma unroll
    for (int cc = 0; cc < 2; ++cc) {
      const int kchunk = dydx * 2 + cc;
      // hoisted swizzled bases; mf adds +2048 (immediate offsets)
      const unsigned ba0 =
          (unsigned)((p0r0 * 128 + cc * 64 + lgo) ^ ((p0r0 & 7) << 4));
      const unsigned ba1 =
          (unsigned)((p0r1 * 128 + cc * 64 + lgo) ^ ((p0r1 & 7) << 4));
      short8v af0[4], af1[4], bfr[2];
#pragma unroll
      for (int nf = 0; nf < 2; ++nf)
        bfr[nf] = *(const short8v*)&btw[kchunk * KCHS + nf * 16 * 32];
#pragma unroll
      for (int mf = 0; mf < 4; ++mf) {
        af0[mf] = *(const short8v*)(rc + ba0 + mf * 2048);
        af1[mf] = *(const short8v*)(rc + ba1 + mf * 2048);
      }
      // swapped operands: D = [oc' x px]
#pragma unroll
      for (int mf = 0; mf < 4; ++mf)
#pragma unroll
        for (int nf = 0; nf < 2; ++nf) {
          acc0[mf][nf] = __builtin_amdgcn_mfma_f32_16x16x32_bf16(
              bfr[nf], af0[mf], acc0[mf][nf], 0, 0, 0);
          acc1[mf][nf] = __builtin_amdgcn_mfma_f32_16x16x32_bf16(
              bfr[nf], af1[mf], acc1[mf][nf], 0, 0, 0);
        }
    }
  }

  // ---- combine, per row, from registers (compile-time acc binding)
  const float* lowb = low + (size_t)b * CC * 16384;
  const float* highb = high + (size_t)b * CC * 4096;
  float* outb = out + (size_t)b * CC * 16384;
  const int xg0 = xh * 64;
  const int c0 = wid * 8 + lg;
  const int c1 = c0 + 4;

  auto combine_row = [&](const f32x4(&ac)[4][2], int y, int gbase) {
    const float by = -1.0f + y * (2.0f / 127.0f);
    const float gyh_b = (by + 1.0f) * 31.5f;
    const float gyl_b = (by + 1.0f) * 63.5f;
#pragma unroll
    for (int mf = 0; mf < 4; ++mf) {
      const int x = xg0 + mf * 16 + lr;
      const float g = gateS[gbase + mf * 16 + lr];
      const float bx = -1.0f + x * (2.0f / 127.0f);
      const float gxh_b = (bx + 1.0f) * 31.5f;
      const float gxl_b = (bx + 1.0f) * 63.5f;

      BSamp sh0 = bprep(highb, (unsigned)(c0 * 4096), HHH, HWW,
                        fmaf(ac[mf][0][0], 63.0f / 256.0f, gxh_b),
                        fmaf(ac[mf][0][1], 63.0f / 256.0f, gyh_b));
      BSamp sl0 = bprep(lowb, (unsigned)(c0 * 16384), LHH, LWW,
                        fmaf(ac[mf][0][2], 127.0f / 256.0f, gxl_b),
                        fmaf(ac[mf][0][3], 127.0f / 256.0f, gyl_b));
      BSamp sh1 = bprep(highb, (unsigned)(c1 * 4096), HHH, HWW,
                        fmaf(ac[mf][1][0], 63.0f / 256.0f, gxh_b),
                        fmaf(ac[mf][1][1], 63.0f / 256.0f, gyh_b));
      BSamp sl1 = bprep(lowb, (unsigned)(c1 * 16384), LHH, LWW,
                        fmaf(ac[mf][1][2], 127.0f / 256.0f, gxl_b),
                        fmaf(ac[mf][1][3], 127.0f / 256.0f, gyl_b));

      float h0 = bfin(sh0), l0 = bfin(sl0);
      outb[(unsigned)(c0 * 16384 + y * 128 + x)] = fmaf(g, h0 - l0, l0);
      float h1 = bfin(sh1), l1 = bfin(sl1);
      outb[(unsigned)(c1 * 16384 + y * 128 + x)] = fmaf(g, h1 - l1, l1);
    }
  };

  combine_row(acc0, y0, 0);
  combine_row(acc1, y0 + 1, 64);
}

// ---------------------------------------------------------------------------
extern "C" void kernel_launch(void* const* d_in, const int* in_sizes, int n_in,
                              void* d_out, int out_size, void* d_ws,
                              size_t ws_size, hipStream_t stream) {
  const float* low = (const float*)d_in[0];
  const float* high = (const float*)d_in[1];
  const float* w_conv_l = (const float*)d_in[2];
  const float* w_conv_h = (const float*)d_in[3];
  const float* w_flow = (const float*)d_in[4];
  const float* w_gate = (const float*)d_in[5];
  float* out = (float*)d_out;
  char* ws = (char*)d_ws;

  const size_t OFF_HSMALL = 0;         //  8,388,608
  const size_t OFF_SUMP = 8388608;     // 17,305,600 (bf16 [b][row][px][ch])
  const size_t OFF_GATEIN = 25694208;  //  2,097,152
  const size_t OFF_BT = 28315648;      //    294,912 (18*256*32 shorts)

  float* h_small = (float*)(ws + OFF_HSMALL);
  unsigned short* sump = (unsigned short*)(ws + OFF_SUMP);
  float* gate_in = (float*)(ws + OFF_GATEIN);
  unsigned short* bt = (unsigned short*)(ws + OFF_BT);

  // K1: dw-high (8192 blocks) + prep_bt (576 blocks appended)
  dw_high_prep_kernel<<<8192 + 576, 256, 0, stream>>>(high, w_conv_h, h_small,
                                                      w_flow, bt);
  // K2: sum + stats + sump borders
  fuse_sum_stats_kernel<<<1024, 512, 0, stream>>>(low, h_small, w_conv_l, sump,
                                                  gate_in);
  // K4: gate conv + flow GEMM + warp + blend (2 rows/block, unroll-pinned)
  flow_gemm_combine_kernel<<<1024, 512, 0, stream>>>(sump, bt, low, high,
                                                     gate_in, w_gate, out);
}